// Round 3
// baseline (96.290 us; speedup 1.0000x reference)
//
#include <hip/hip_runtime.h>
#include <math.h>

// ChamferDistanceL1: B=8, N=M=4096, fp32.
// R9: FUSED single-pass dual reduction. R8 proved the 256MiB ws poison-fill
// (~40us) is unconditional (present even with d_ws never written) -> only
// lever is the 39.9us chamfer kernel (VALUBusy 89.6%, pure VALU-bound).
// Old structure computed every unique pair TWICE (dir=0/dir=1). Now one
// pass computes d(x_i,y_j) once, feeding BOTH min_j (x-side, lane-local)
// and min_i (y-side, 8-lane shfl_xor group reduce). Block-partial y-mins
// -> d_ws (free: it's poisoned anyway), reduced by tiny pass-2 kernel.
// Cost/unique-pair ~6.9 VALU vs 11 -> predict fused ~25us, total ~72us.
// Groups are 8 lanes x QPT=8 (QPB=64 unchanged); per-point ds_read halved.

#define BLK 512
#define QPB 64        // queries (x) per block
#define LPG 8         // lanes per group
#define NGRP (BLK / LPG)       // 64 groups
#define QPT 8         // queries per thread (8 lanes * 8 = 64)
#define SLICE 1024    // db (y) points staged in LDS per slice
#define GRANGE (SLICE / NGRP)  // 16 points per group per slice
#define NWAVE (BLK / 64)       // 8

__global__ void zero_out_kernel(float* __restrict__ out) { out[0] = 0.0f; }

// ---------------- fused kernel (N == M == 4096 only) ----------------
__global__ __launch_bounds__(BLK) void chamfer_fused_kernel(
    const float* __restrict__ x, const float* __restrict__ y,
    float* __restrict__ out, float* __restrict__ wsY, float sx) {
  __shared__ float4 sdb[NGRP][GRANGE + 1];  // 64*17*16 B = 17.4 KB
  __shared__ float pmin[NWAVE][QPB];        // 2 KB

  const int b = blockIdx.y;
  const int xblk = blockIdx.x;
  const float* __restrict__ qb  = x + (size_t)b * 4096 * 3;
  const float* __restrict__ dbb = y + (size_t)b * 4096 * 3;

  const int t = threadIdx.x;
  const int g = t >> 3;  // group id [0,64)
  const int u = t & 7;   // lane-in-group

  const int q0 = xblk * QPB;
  float qx[QPT], qy[QPT], qz[QPT], dmin[QPT];
#pragma unroll
  for (int k = 0; k < QPT; ++k) {
    const int qi = q0 + u + 8 * k;
    qx[k] = qb[3 * qi + 0];
    qy[k] = qb[3 * qi + 1];
    qz[k] = qb[3 * qi + 2];
    dmin[k] = 3.0e38f;
  }

  // yacc[si*2+h]: this lane's final block-min for y-point
  //   si*1024 + g*16 + h*8 + u   (si = slice, h = half)
  float yacc[8];

#pragma unroll
  for (int si = 0; si < 4; ++si) {
    const int s0 = si * SLICE;
    // ---- stage SLICE y-points into LDS ----
#pragma unroll
    for (int r = 0; r < SLICE / BLK; ++r) {
      const int p = t + r * BLK;
      const int j = s0 + p;
      sdb[p >> 4][p & 15] =
          make_float4(dbb[3 * j + 0], dbb[3 * j + 1], dbb[3 * j + 2], 0.0f);
    }
    __syncthreads();

    // ---- scan this group's GRANGE points against all 64 queries ----
#pragma unroll
    for (int tt = 0; tt < GRANGE; tt += 2) {
      const float4 p0 = sdb[g][tt];
      const float4 p1 = sdb[g][tt + 1];
      float d0[QPT], d1[QPT];
#pragma unroll
      for (int k = 0; k < QPT; ++k) {
        d0[k] =
            fabsf(qx[k] - p0.x) + fabsf(qy[k] - p0.y) + fabsf(qz[k] - p0.z);
        d1[k] =
            fabsf(qx[k] - p1.x) + fabsf(qy[k] - p1.y) + fabsf(qz[k] - p1.z);
        dmin[k] = fminf(dmin[k], fminf(d0[k], d1[k]));  // v_min3_f32
      }
      // y-side: per-point min over this lane's 8 queries, then over 8 lanes
      float y0 = fminf(fminf(fminf(d0[0], d0[1]), fminf(d0[2], d0[3])),
                       fminf(fminf(d0[4], d0[5]), fminf(d0[6], d0[7])));
      float y1 = fminf(fminf(fminf(d1[0], d1[1]), fminf(d1[2], d1[3])),
                       fminf(fminf(d1[4], d1[5]), fminf(d1[6], d1[7])));
      y0 = fminf(y0, __shfl_xor(y0, 1, 64));
      y0 = fminf(y0, __shfl_xor(y0, 2, 64));
      y0 = fminf(y0, __shfl_xor(y0, 4, 64));
      y1 = fminf(y1, __shfl_xor(y1, 1, 64));
      y1 = fminf(y1, __shfl_xor(y1, 2, 64));
      y1 = fminf(y1, __shfl_xor(y1, 4, 64));
      // keeper lane u == point&7 stashes the final (static reg index)
      const int idx = si * 2 + (tt >> 3);  // (tt+1)>>3 == tt>>3 for even tt
      yacc[idx] = (u == (tt & 7)) ? y0 : yacc[idx];
      yacc[idx] = (u == ((tt + 1) & 7)) ? y1 : yacc[idx];
    }
    __syncthreads();
  }

  // ---- y-side: store per-block partial mins (coalesced-ish, 8/thread) ----
  float* __restrict__ wyb = wsY + ((size_t)b * 64 + xblk) * 4096;
#pragma unroll
  for (int si = 0; si < 4; ++si) {
#pragma unroll
    for (int h = 0; h < 2; ++h) {
      wyb[si * 1024 + g * 16 + h * 8 + u] = yacc[si * 2 + h];
    }
  }

  // ---- x-side: combine the 8 groups inside each wave (lane bits 3,4,5) ----
#pragma unroll
  for (int k = 0; k < QPT; ++k) {
    float m = dmin[k];
    m = fminf(m, __shfl_xor(m, 8, 64));
    m = fminf(m, __shfl_xor(m, 16, 64));
    m = fminf(m, __shfl_xor(m, 32, 64));
    dmin[k] = m;
  }
  const int w = t >> 6;
  if ((t & 63) < 8) {
#pragma unroll
    for (int k = 0; k < QPT; ++k) pmin[w][u + 8 * k] = dmin[k];
  }
  __syncthreads();

  // ---- cross-wave min, sum 64 finals, one atomic per block ----
  if (t < QPB) {
    float m = pmin[0][t];
#pragma unroll
    for (int ww = 1; ww < NWAVE; ++ww) m = fminf(m, pmin[ww][t]);
#pragma unroll
    for (int o = 32; o > 0; o >>= 1) m += __shfl_down(m, o, 64);
    if (t == 0) atomicAdd(out, m * sx);
  }
}

// ---------------- pass 2: reduce y-side partials ----------------
__global__ __launch_bounds__(256) void chamfer_ymin_kernel(
    const float* __restrict__ wsY, float* __restrict__ out, float sy) {
  const int tid = blockIdx.x * 256 + threadIdx.x;  // [0, 8*4096)
  const int b = tid >> 12;
  const int j = tid & 4095;
  const float* __restrict__ p = wsY + (size_t)b * 64 * 4096 + j;
  float m = 3.0e38f;
#pragma unroll 8
  for (int xb = 0; xb < 64; ++xb) m = fminf(m, p[(size_t)xb * 4096]);
  float s = m * sy;
#pragma unroll
  for (int o = 32; o > 0; o >>= 1) s += __shfl_down(s, o, 64);
  __shared__ float ws[4];
  const int w = threadIdx.x >> 6;
  if ((threadIdx.x & 63) == 0) ws[w] = s;
  __syncthreads();
  if (threadIdx.x == 0) atomicAdd(out, ws[0] + ws[1] + ws[2] + ws[3]);
}

// ---------------- generic fallback (any N, M): R8 two-dir kernel ----------
#define GBLK 512
#define GQPB 64
#define GQPT 4
#define GSLICE 1024
#define GNGRP 32
#define GGRANGE (GSLICE / GNGRP)

__global__ __launch_bounds__(GBLK) void chamfer_generic_kernel(
    const float* __restrict__ x, const float* __restrict__ y,
    float* __restrict__ out, int N, int M, float sx, float sy) {
  __shared__ float4 sdb[GNGRP][GGRANGE + 1];
  __shared__ float pmin[GBLK / 64][GQPB];
  const int dir = blockIdx.z;
  const int b = blockIdx.y;
  const float* __restrict__ q  = dir ? y : x;
  const float* __restrict__ db = dir ? x : y;
  const int Nq  = dir ? M : N;
  const int Ndb = dir ? N : M;
  const float scale = dir ? sy : sx;
  const float* __restrict__ qb  = q  + (size_t)b * Nq  * 3;
  const float* __restrict__ dbb = db + (size_t)b * Ndb * 3;
  const int t = threadIdx.x;
  const int g = t >> 4, u = t & 15;
  const int q0 = blockIdx.x * GQPB;
  float qx[GQPT], qy[GQPT], qz[GQPT], dmin[GQPT];
#pragma unroll
  for (int k = 0; k < GQPT; ++k) {
    int qi = q0 + u + 16 * k;
    if (qi >= Nq) qi = Nq - 1;
    qx[k] = qb[3 * qi + 0];
    qy[k] = qb[3 * qi + 1];
    qz[k] = qb[3 * qi + 2];
    dmin[k] = 3.0e38f;
  }
  for (int s0 = 0; s0 < Ndb; s0 += GSLICE) {
    const int send = min(GSLICE, Ndb - s0);
    for (int p = t; p < send; p += GBLK) {
      const int j = s0 + p;
      sdb[p >> 5][p & 31] =
          make_float4(dbb[3 * j + 0], dbb[3 * j + 1], dbb[3 * j + 2], 0.0f);
    }
    __syncthreads();
    const int base = g * GGRANGE;
    const int lim = min(GGRANGE, max(0, send - base));
    for (int tt = 0; tt < lim; ++tt) {
      const float4 p0 = sdb[g][tt];
#pragma unroll
      for (int k = 0; k < GQPT; ++k) {
        const float d0 =
            fabsf(qx[k] - p0.x) + fabsf(qy[k] - p0.y) + fabsf(qz[k] - p0.z);
        dmin[k] = fminf(dmin[k], d0);
      }
    }
    __syncthreads();
  }
#pragma unroll
  for (int k = 0; k < GQPT; ++k) {
    float m = dmin[k];
    m = fminf(m, __shfl_xor(m, 16, 64));
    m = fminf(m, __shfl_xor(m, 32, 64));
    dmin[k] = m;
  }
  const int w = t >> 6, l = t & 63;
  if (l < 16) {
#pragma unroll
    for (int k = 0; k < GQPT; ++k) pmin[w][l + 16 * k] = dmin[k];
  }
  __syncthreads();
  if (t < GQPB) {
    float m = pmin[0][t];
#pragma unroll
    for (int ww = 1; ww < GBLK / 64; ++ww) m = fminf(m, pmin[ww][t]);
    if (q0 + t >= Nq) m = 0.0f;
#pragma unroll
    for (int o = 32; o > 0; o >>= 1) m += __shfl_down(m, o, 64);
    if (t == 0) atomicAdd(out, m * scale);
  }
}

extern "C" void kernel_launch(void* const* d_in, const int* in_sizes, int n_in,
                              void* d_out, int out_size, void* d_ws, size_t ws_size,
                              hipStream_t stream) {
  const float* x = (const float*)d_in[0];
  const float* y = (const float*)d_in[1];
  const int B = 8;
  const int N = in_sizes[0] / (B * 3);
  const int M = in_sizes[1] / (B * 3);

  float* out = (float*)d_out;
  float* wsY = (float*)d_ws;  // 8*64*4096 floats = 8 MB (ws is poisoned by
                              // the harness anyway; using it is free)
  const float sx = 1.0f / (float)(B * N);
  const float sy = 1.0f / (float)(B * M);

  zero_out_kernel<<<1, 1, 0, stream>>>(out);

  if (N == 4096 && M == 4096) {
    dim3 grd(4096 / QPB, B);  // 64 x-tiles * 8 batches = 512 blocks
    chamfer_fused_kernel<<<grd, dim3(BLK), 0, stream>>>(x, y, out, wsY, sx);
    chamfer_ymin_kernel<<<(8 * 4096) / 256, 256, 0, stream>>>(wsY, out, sy);
  } else {
    const int mx = (N > M) ? N : M;
    dim3 grd((mx + GQPB - 1) / GQPB, B, 2);
    chamfer_generic_kernel<<<grd, dim3(GBLK), 0, stream>>>(
        x, y, out, N, M, sx, sy);
  }
}